// Round 15
// baseline (246.947 us; speedup 1.0000x reference)
//
#include <hip/hip_runtime.h>
#include <hip/hip_fp16.h>

// GCN 3-layer: x -> GCNConv(W1)+BN+ReLU -> GCNConv(W2)+BN+ReLU -> GCNConv(W3)
// CSR: 1 u64 atomic/edge (R17 source-third order), rank u8. k_mega: atomic
// stream || LDS-staged gemm1 (R23: W1->LDS once/block; k_mega 50.7 -> <44,
// and the RMW stream sped up too -- gemm1's old scattered L2 reads were
// contending with it). Gather ledger: scheduling null (R13-R16), locality
// saturated (R17), int8 rows -9.5us (R21) with a large width-independent
// residual => REQUEST COUNT suspected.
// R24: 16B-REQUEST GATHER. aggr_mm reworked to 32 nodes/block, 6 lanes x
// uint4(16B) per 96B row (was 12 x 8B): same bytes, same lines, HALF the
// requests/edge. Node-residency unchanged (1563x32 = 50016 ~ 3125x16), so
// R13's TLP hazard doesn't apply. aggr3 (already 16B lanes) = control.
// Discriminator: request-slot-bound -> aggr_mm -30%; line-bound -> null.

constexpr float BN_EPS = 1e-5f;
constexpr float DEG_SCALE = 131072.0f;            // 2^17 (weighted degree, 24-bit field)
constexpr float INV_DEG_SCALE = 1.0f / 131072.0f;
constexpr float NORM_SCALE = 32768.0f;            // 2^15 (edge norm quant)
constexpr float INV_NORM_SCALE = 1.0f / 32768.0f;

typedef _Float16 f16x8 __attribute__((ext_vector_type(8)));
typedef float f32x4 __attribute__((ext_vector_type(4)));

// ---------------- gemm1 (k_mega role): [64x128]@W1^T -> int8 rows + scale ----
// lds: union buffer, 96*136 = 13056 halves (26112B).

__device__ __forceinline__ void gemm1_q(const float* __restrict__ x,
                                        const float* __restrict__ W1,
                                        unsigned char* __restrict__ t1q,
                                        float* __restrict__ scl1,
                                        int n0b, int tid, int n,
                                        _Float16* lds, unsigned* rmaxb) {
    constexpr int LROW = 104;
    constexpr int WROW = 136;
    if (tid < 64) rmaxb[tid] = 0u;
    for (int i = tid; i < 96 * 128; i += 256) {
        int row = i >> 7, col = i & 127;
        lds[row * WROW + col] = (_Float16)W1[i];
    }
    __syncthreads();

    int wave = tid >> 6, lane = tid & 63, quad = lane >> 4, r = lane & 15;
    int n0 = n0b + wave * 16;
    bool active = (n0 < n);             // N%16==0: active waves fully in-bounds
    f32x4 acc[6];
    if (active) {
        f16x8 a[4];
        const float* xr = x + (size_t)(n0 + r) * 128 + quad * 8;
#pragma unroll
        for (int kt = 0; kt < 4; ++kt) {
            float4 v0 = *(const float4*)(xr + kt * 32);
            float4 v1 = *(const float4*)(xr + kt * 32 + 4);
            f16x8 t = {(_Float16)v0.x, (_Float16)v0.y, (_Float16)v0.z, (_Float16)v0.w,
                       (_Float16)v1.x, (_Float16)v1.y, (_Float16)v1.z, (_Float16)v1.w};
            a[kt] = t;
        }
#pragma unroll
        for (int ft = 0; ft < 6; ++ft) acc[ft] = (f32x4){0.f, 0.f, 0.f, 0.f};
#pragma unroll
        for (int kt = 0; kt < 4; ++kt) {
#pragma unroll
            for (int ft = 0; ft < 6; ++ft) {
                f16x8 b = *(const f16x8*)(lds + (size_t)(ft * 16 + r) * WROW + kt * 32 + quad * 8);
                acc[ft] = __builtin_amdgcn_mfma_f32_16x16x32_f16(a[kt], b, acc[ft], 0, 0, 0);
            }
        }
    }
    __syncthreads();                    // all B-reads done before buffer reuse
    if (active) {
#pragma unroll
        for (int ft = 0; ft < 6; ++ft)
#pragma unroll
            for (int reg = 0; reg < 4; ++reg)
                lds[(size_t)(wave * 16 + quad * 4 + reg) * LROW + ft * 16 + r] =
                    (_Float16)acc[ft][reg];
    }
    __syncthreads();
    {   // row absmax: 64 rows x 4 quarters (24 vals)
        int row = tid >> 2, qt = tid & 3;
        const _Float16* lp = lds + (size_t)row * LROW + qt * 24;
        float mx = 0.f;
#pragma unroll
        for (int j = 0; j < 24; ++j) mx = fmaxf(mx, fabsf((float)lp[j]));
        atomicMax(&rmaxb[row], __float_as_uint(mx));
    }
    __syncthreads();
    for (int i = tid; i < 64 * 12; i += 256) {   // quantize + store
        int row = i / 12, c = i - row * 12;
        int grow = n0b + row;
        if (grow >= n) continue;
        float rm = __uint_as_float(rmaxb[row]);
        float inv = (rm > 0.f) ? 127.0f / rm : 0.f;
        const _Float16* lp = lds + (size_t)row * LROW + c * 8;
        unsigned lo = 0, hi = 0;
#pragma unroll
        for (int j = 0; j < 4; ++j) {
            int qv = __float2int_rn((float)lp[j] * inv);
            qv = qv > 127 ? 127 : (qv < -127 ? -127 : qv);
            lo |= ((unsigned)qv & 255u) << (8 * j);
        }
#pragma unroll
        for (int j = 0; j < 4; ++j) {
            int qv = __float2int_rn((float)lp[4 + j] * inv);
            qv = qv > 127 ? 127 : (qv < -127 ? -127 : qv);
            hi |= ((unsigned)qv & 255u) << (8 * j);
        }
        *(uint2*)(t1q + (size_t)grow * 96 + c * 8) = make_uint2(lo, hi);
        if (c == 0) scl1[grow] = rm * (1.0f / 127.0f);
    }
}

// ---------------- mega: interleaved deg atomics | GEMM1(int8) | W convert -----

__global__ __launch_bounds__(256) void k_mega(
    const int* __restrict__ row_idx, const int* __restrict__ col_idx,
    const float* __restrict__ ew,
    unsigned long long* packed, unsigned char* rank, int e_cnt, int pair_b,
    int t1, int t2,
    const float* __restrict__ x, const float* __restrict__ W1,
    unsigned char* __restrict__ t1q, float* __restrict__ scl1, int n,
    const float* __restrict__ W2, const float* __restrict__ W3,
    _Float16* __restrict__ w2h, _Float16* __restrict__ w3h,
    int w2n4, int w3n4) {
    __shared__ _Float16 lds[96 * 136];     // union: W1 stage / epilogue rows
    __shared__ unsigned rmaxb[64];
    int b = blockIdx.x;
    if (b < 2 * pair_b) {
        int q = b >> 1;
        if ((b & 1) == 0) {
            // deg role: 1024 edges per block (4 independent atomics/thread)
#pragma unroll
            for (int j = 0; j < 4; ++j) {
                int e = q * 1024 + j * 256 + (int)threadIdx.x;
                if (e < e_cnt) {
                    int c = col_idx[e];
                    int r = row_idx[e];
                    int t = (r >= t2) ? 2 : ((r >= t1) ? 1 : 0);
                    int sh = 24 + 10 * t;
                    unsigned wfix = (unsigned)(ew[e] * DEG_SCALE + 0.5f);
                    unsigned long long inc = (1ull << sh) | (unsigned long long)wfix;
                    unsigned long long old = atomicAdd(&packed[c], inc);
                    rank[e] = (unsigned char)((old >> sh) & 0x3FFull);
                }
            }
        } else {
            gemm1_q(x, W1, t1q, scl1, q * 64, (int)threadIdx.x, n, lds, rmaxb);
        }
    } else {
        // convert role: W2|W3 fp32->fp16
        int i = (b - 2 * pair_b) * 256 + (int)threadIdx.x;
        const float* src; _Float16* dst; int o;
        if (i < w2n4) { src = W2; dst = w2h; o = i; }
        else if (i < w2n4 + w3n4) { src = W3; dst = w3h; o = i - w2n4; }
        else return;
        float4 v = ((const float4*)src)[o];
        __half2 h0 = __floats2half2_rn(v.x, v.y);
        __half2 h1 = __floats2half2_rn(v.z, v.w);
        *(uint2*)(dst + (size_t)o * 4) = make_uint2(*(unsigned*)&h0, *(unsigned*)&h1);
    }
}

// ---------------- scans ----------------

__device__ __forceinline__ int pk_cnt(unsigned long long p) {
    return (int)((p >> 24) & 0x3FF) + (int)((p >> 34) & 0x3FF) + (int)((p >> 44) & 0x3FF);
}

__global__ void k_scan1(const unsigned long long* __restrict__ packed,
                        int* bsum, float* dis, int n) {
    __shared__ int s[256];
    int i = blockIdx.x * 256 + threadIdx.x;
    int cnt = 0;
    if (i < n) {
        unsigned long long p = packed[i];
        cnt = pk_cnt(p);
        float wsum = (float)(unsigned)(p & 0xFFFFFFull) * INV_DEG_SCALE;
        dis[i] = rsqrtf(1.0f + wsum);   // self-loop weight 1 included
    }
    s[threadIdx.x] = cnt;
    __syncthreads();
    for (int off = 128; off > 0; off >>= 1) {
        if ((int)threadIdx.x < off) s[threadIdx.x] += s[threadIdx.x + off];
        __syncthreads();
    }
    if (threadIdx.x == 0) bsum[blockIdx.x] = s[0];
}

__global__ void k_scan23(const unsigned long long* __restrict__ packed,
                         const int* __restrict__ bsum,
                         int* row_ptr, int n, int e_total, int nb) {
    __shared__ int sb[256];
    __shared__ int s[256];
    int t = threadIdx.x;
    int bv = (t < nb) ? bsum[t] : 0;
    sb[t] = bv;
    __syncthreads();
    for (int off = 1; off < 256; off <<= 1) {
        int x = (t >= off) ? sb[t - off] : 0;
        __syncthreads();
        sb[t] += x;
        __syncthreads();
    }
    int boff = (blockIdx.x == 0) ? 0 : sb[blockIdx.x - 1];

    int i = blockIdx.x * 256 + t;
    int v = (i < n) ? pk_cnt(packed[i]) : 0;
    s[t] = v;
    __syncthreads();
    for (int off = 1; off < 256; off <<= 1) {
        int x = (t >= off) ? s[t - off] : 0;
        __syncthreads();
        s[t] += x;
        __syncthreads();
    }
    int ex = s[t] - v + boff;
    if (i < n) row_ptr[i] = ex;
    if (i == 0) row_ptr[n] = e_total;
}

__global__ void k_fill(const int* __restrict__ row_idx, const int* __restrict__ col_idx,
                       const float* __restrict__ ew, const float* __restrict__ dis,
                       const int* __restrict__ row_ptr, const unsigned char* __restrict__ rank,
                       const unsigned long long* __restrict__ packed,
                       unsigned* ep, int e_cnt, int t1, int t2) {
    int e = blockIdx.x * 256 + threadIdx.x;
    if (e < e_cnt) {
        int r = row_idx[e];
        int c = col_idx[e];
        unsigned long long p = packed[c];          // 400KB table: L2-resident
        int c0 = (int)((p >> 24) & 0x3FF);
        int c1 = (int)((p >> 34) & 0x3FF);
        int t = (r >= t2) ? 2 : ((r >= t1) ? 1 : 0);
        int off = (t > 0 ? c0 : 0) + (t > 1 ? c1 : 0);
        float nm = dis[r] * ew[e];                 // dis[c] factored into aggr
        unsigned q = (unsigned)(nm * NORM_SCALE + 0.5f);
        if (q > 65535u) q = 65535u;
        ep[row_ptr[c] + off + (int)rank[e]] = ((unsigned)r << 16) | q;
    }
}

// ---------------- aggregation helpers ----------------

__device__ inline void cvt8(uint4 u, float* f) {
    float2 t;
    t = __half22float2(*(const __half2*)&u.x); f[0] = t.x; f[1] = t.y;
    t = __half22float2(*(const __half2*)&u.y); f[2] = t.x; f[3] = t.y;
    t = __half22float2(*(const __half2*)&u.z); f[4] = t.x; f[5] = t.y;
    t = __half22float2(*(const __half2*)&u.w); f[6] = t.x; f[7] = t.y;
}

__device__ inline void h8_acc(uint4 u, float w, float acc[8]) {
    float2 a = __half22float2(*(const __half2*)&u.x);
    float2 b = __half22float2(*(const __half2*)&u.y);
    float2 c = __half22float2(*(const __half2*)&u.z);
    float2 d = __half22float2(*(const __half2*)&u.w);
    acc[0] = fmaf(w, a.x, acc[0]); acc[1] = fmaf(w, a.y, acc[1]);
    acc[2] = fmaf(w, b.x, acc[2]); acc[3] = fmaf(w, b.y, acc[3]);
    acc[4] = fmaf(w, c.x, acc[4]); acc[5] = fmaf(w, c.y, acc[5]);
    acc[6] = fmaf(w, d.x, acc[6]); acc[7] = fmaf(w, d.y, acc[7]);
}

// 16 int8 features (one uint4) -> acc[16], ws = edge_norm * row_scale
__device__ inline void q16_acc(uint4 v, float ws, float acc[16]) {
    int a = (int)v.x, b = (int)v.y, c = (int)v.z, d = (int)v.w;
    acc[0]  = fmaf(ws, (float)(int)(char)(a      ), acc[0]);
    acc[1]  = fmaf(ws, (float)(int)(char)(a >>  8), acc[1]);
    acc[2]  = fmaf(ws, (float)(int)(char)(a >> 16), acc[2]);
    acc[3]  = fmaf(ws, (float)(a >> 24),            acc[3]);
    acc[4]  = fmaf(ws, (float)(int)(char)(b      ), acc[4]);
    acc[5]  = fmaf(ws, (float)(int)(char)(b >>  8), acc[5]);
    acc[6]  = fmaf(ws, (float)(int)(char)(b >> 16), acc[6]);
    acc[7]  = fmaf(ws, (float)(b >> 24),            acc[7]);
    acc[8]  = fmaf(ws, (float)(int)(char)(c      ), acc[8]);
    acc[9]  = fmaf(ws, (float)(int)(char)(c >>  8), acc[9]);
    acc[10] = fmaf(ws, (float)(int)(char)(c >> 16), acc[10]);
    acc[11] = fmaf(ws, (float)(c >> 24),            acc[11]);
    acc[12] = fmaf(ws, (float)(int)(char)(d      ), acc[12]);
    acc[13] = fmaf(ws, (float)(int)(char)(d >>  8), acc[13]);
    acc[14] = fmaf(ws, (float)(int)(char)(d >> 16), acc[14]);
    acc[15] = fmaf(ws, (float)(d >> 24),            acc[15]);
}

// int8 gather, 16B requests: one uint4 per edge per lane
__device__ __forceinline__ void gather_row_q16(const unsigned char* __restrict__ tq,
                                               const float* __restrict__ scl,
                                               const unsigned* __restrict__ ep,
                                               int e0, int e1, int q, float acc[16]) {
    int e = e0;
    for (; e + 4 <= e1; e += 4) {
        unsigned p0 = ep[e + 0], p1 = ep[e + 1], p2 = ep[e + 2], p3 = ep[e + 3];
        uint4 v0 = *(const uint4*)(tq + (size_t)(p0 >> 16) * 96 + q * 16);
        uint4 v1 = *(const uint4*)(tq + (size_t)(p1 >> 16) * 96 + q * 16);
        uint4 v2 = *(const uint4*)(tq + (size_t)(p2 >> 16) * 96 + q * 16);
        uint4 v3 = *(const uint4*)(tq + (size_t)(p3 >> 16) * 96 + q * 16);
        float s0 = scl[p0 >> 16], s1 = scl[p1 >> 16];
        float s2 = scl[p2 >> 16], s3 = scl[p3 >> 16];
        q16_acc(v0, (float)(p0 & 0xffffu) * INV_NORM_SCALE * s0, acc);
        q16_acc(v1, (float)(p1 & 0xffffu) * INV_NORM_SCALE * s1, acc);
        q16_acc(v2, (float)(p2 & 0xffffu) * INV_NORM_SCALE * s2, acc);
        q16_acc(v3, (float)(p3 & 0xffffu) * INV_NORM_SCALE * s3, acc);
    }
    for (; e < e1; ++e) {
        unsigned p = ep[e];
        uint4 v = *(const uint4*)(tq + (size_t)(p >> 16) * 96 + q * 16);
        q16_acc(v, (float)(p & 0xffffu) * INV_NORM_SCALE * scl[p >> 16], acc);
    }
}

// fp16 gather (layer-3 table, 64-wide) -- unchanged control
template <int FQ>
__device__ __forceinline__ void gather_row(const uint4* __restrict__ base,
                                           const unsigned* __restrict__ ep,
                                           int e0, int e1, int q, float acc[8]) {
    int e = e0;
    for (; e + 8 <= e1; e += 8) {
        unsigned p0 = ep[e + 0], p1 = ep[e + 1], p2 = ep[e + 2], p3 = ep[e + 3];
        unsigned p4 = ep[e + 4], p5 = ep[e + 5], p6 = ep[e + 6], p7 = ep[e + 7];
        uint4 x0 = base[(size_t)(p0 >> 16) * FQ + q];
        uint4 x1 = base[(size_t)(p1 >> 16) * FQ + q];
        uint4 x2 = base[(size_t)(p2 >> 16) * FQ + q];
        uint4 x3 = base[(size_t)(p3 >> 16) * FQ + q];
        uint4 x4 = base[(size_t)(p4 >> 16) * FQ + q];
        uint4 x5 = base[(size_t)(p5 >> 16) * FQ + q];
        uint4 x6 = base[(size_t)(p6 >> 16) * FQ + q];
        uint4 x7 = base[(size_t)(p7 >> 16) * FQ + q];
        h8_acc(x0, (float)(p0 & 0xffffu) * INV_NORM_SCALE, acc);
        h8_acc(x1, (float)(p1 & 0xffffu) * INV_NORM_SCALE, acc);
        h8_acc(x2, (float)(p2 & 0xffffu) * INV_NORM_SCALE, acc);
        h8_acc(x3, (float)(p3 & 0xffffu) * INV_NORM_SCALE, acc);
        h8_acc(x4, (float)(p4 & 0xffffu) * INV_NORM_SCALE, acc);
        h8_acc(x5, (float)(p5 & 0xffffu) * INV_NORM_SCALE, acc);
        h8_acc(x6, (float)(p6 & 0xffffu) * INV_NORM_SCALE, acc);
        h8_acc(x7, (float)(p7 & 0xffffu) * INV_NORM_SCALE, acc);
    }
    for (; e + 4 <= e1; e += 4) {
        unsigned p0 = ep[e + 0], p1 = ep[e + 1], p2 = ep[e + 2], p3 = ep[e + 3];
        uint4 x0 = base[(size_t)(p0 >> 16) * FQ + q];
        uint4 x1 = base[(size_t)(p1 >> 16) * FQ + q];
        uint4 x2 = base[(size_t)(p2 >> 16) * FQ + q];
        uint4 x3 = base[(size_t)(p3 >> 16) * FQ + q];
        h8_acc(x0, (float)(p0 & 0xffffu) * INV_NORM_SCALE, acc);
        h8_acc(x1, (float)(p1 & 0xffffu) * INV_NORM_SCALE, acc);
        h8_acc(x2, (float)(p2 & 0xffffu) * INV_NORM_SCALE, acc);
        h8_acc(x3, (float)(p3 & 0xffffu) * INV_NORM_SCALE, acc);
    }
    for (; e < e1; ++e) {
        unsigned p = ep[e];
        uint4 xv = base[(size_t)(p >> 16) * FQ + q];
        h8_acc(xv, (float)(p & 0xffffu) * INV_NORM_SCALE, acc);
    }
}

// ------ fused: int8-aggregate(96, 16B reqs) + BN + ReLU + [32x96]@W^T ---------
// Block = 192 thr = 32 nodes x 6 chunk-lanes (16B each). Node-residency equals
// the old 16x12 layout (50016 vs 50000); requests/edge halve. MFMA phase:
// waves 0,1 each compute a 16-row tile; wave 2 idles (~100cyc, hidden).

template <int FOUT, bool QOUT>
__global__ __launch_bounds__(192) void k_aggr_mm(
    const unsigned char* __restrict__ tq, const float* __restrict__ scl,
    const int* __restrict__ row_ptr, const unsigned* __restrict__ ep,
    const float* __restrict__ dis, const float* __restrict__ bias,
    const float* __restrict__ g, const float* __restrict__ beta,
    const float* __restrict__ m, const float* __restrict__ v,
    const _Float16* __restrict__ Wh,       // [FOUT][96] fp16
    void* __restrict__ Yout, float* __restrict__ sclo, int n) {
    constexpr int LROW = 104;
    __shared__ _Float16 lds[32 * LROW];
    __shared__ unsigned rmaxb[32];
    int tid = (int)threadIdx.x;
    int n0b = blockIdx.x * 32;
    int nl = tid / 6;                      // 0..31
    int q = tid - nl * 6;                  // 0..5 (16B chunk)
    int node = n0b + nl;
    if (QOUT && tid < 32) rmaxb[tid] = 0u;

    if (node < n) {
        float d = dis[node];
        float acc[16];
#pragma unroll
        for (int j = 0; j < 16; ++j) acc[j] = 0.f;
        {
            uint4 sv = *(const uint4*)(tq + (size_t)node * 96 + q * 16);
            q16_acc(sv, d * scl[node], acc);
        }
        gather_row_q16(tq, scl, ep, row_ptr[node], row_ptr[node + 1], q, acc);

        int fb = q * 16;
        const float4* bb = (const float4*)(bias + fb);
        float4 b0 = bb[0], b1 = bb[1], b2 = bb[2], b3 = bb[3];
        acc[0]  = fmaf(acc[0],  d, b0.x); acc[1]  = fmaf(acc[1],  d, b0.y);
        acc[2]  = fmaf(acc[2],  d, b0.z); acc[3]  = fmaf(acc[3],  d, b0.w);
        acc[4]  = fmaf(acc[4],  d, b1.x); acc[5]  = fmaf(acc[5],  d, b1.y);
        acc[6]  = fmaf(acc[6],  d, b1.z); acc[7]  = fmaf(acc[7],  d, b1.w);
        acc[8]  = fmaf(acc[8],  d, b2.x); acc[9]  = fmaf(acc[9],  d, b2.y);
        acc[10] = fmaf(acc[10], d, b2.z); acc[11] = fmaf(acc[11], d, b2.w);
        acc[12] = fmaf(acc[12], d, b3.x); acc[13] = fmaf(acc[13], d, b3.y);
        acc[14] = fmaf(acc[14], d, b3.z); acc[15] = fmaf(acc[15], d, b3.w);
#pragma unroll
        for (int j = 0; j < 16; ++j) {
            acc[j] = fmaxf((acc[j] - m[fb + j]) * rsqrtf(v[fb + j] + BN_EPS) * g[fb + j]
                           + beta[fb + j], 0.f);
        }
        _Float16* dst = lds + (size_t)nl * LROW + fb;
        __half2 h0 = __floats2half2_rn(acc[0],  acc[1]);
        __half2 h1 = __floats2half2_rn(acc[2],  acc[3]);
        __half2 h2 = __floats2half2_rn(acc[4],  acc[5]);
        __half2 h3 = __floats2half2_rn(acc[6],  acc[7]);
        __half2 h4 = __floats2half2_rn(acc[8],  acc[9]);
        __half2 h5 = __floats2half2_rn(acc[10], acc[11]);
        __half2 h6 = __floats2half2_rn(acc[12], acc[13]);
        __half2 h7 = __floats2half2_rn(acc[14], acc[15]);
        *(uint4*)(dst + 0) = make_uint4(*(unsigned*)&h0, *(unsigned*)&h1,
                                        *(unsigned*)&h2, *(unsigned*)&h3);
        *(uint4*)(dst + 8) = make_uint4(*(unsigned*)&h4, *(unsigned*)&h5,
                                        *(unsigned*)&h6, *(unsigned*)&h7);
    }
    __syncthreads();

    // ---- MFMA phase: waves 0,1 -> two [16x96]@Wh^T tiles ----
    constexpr int FT = FOUT / 16;
    f32x4 cacc[FT];
    int w = tid >> 6;
    int lane = tid & 63, quad = lane >> 4, r = lane & 15;
    if (w < 2) {
        f16x8 a[3];
#pragma unroll
        for (int kt = 0; kt < 3; ++kt)
            a[kt] = *(const f16x8*)(lds + (size_t)(w * 16 + r) * LROW + kt * 32 + quad * 8);
#pragma unroll
        for (int ft = 0; ft < FT; ++ft) cacc[ft] = (f32x4){0.f, 0.f, 0.f, 0.f};
#pragma unroll
        for (int kt = 0; kt < 3; ++kt) {
#pragma unroll
            for (int ft = 0; ft < FT; ++ft) {
                f16x8 b = *(const f16x8*)(Wh + (size_t)(ft * 16 + r) * 96 + kt * 32 + quad * 8);
                cacc[ft] = __builtin_amdgcn_mfma_f32_16x16x32_f16(a[kt], b, cacc[ft], 0, 0, 0);
            }
        }
    }
    __syncthreads();           // all A reads complete before overwrite
    if (w < 2) {
#pragma unroll
        for (int ft = 0; ft < FT; ++ft)
#pragma unroll
            for (int reg = 0; reg < 4; ++reg)
                lds[(size_t)(w * 16 + quad * 4 + reg) * LROW + ft * 16 + r] =
                    (_Float16)cacc[ft][reg];
    }
    __syncthreads();

    if (QOUT) {
        // row absmax over FOUT=96: 32 rows x 4 quarters = 128 tasks
        if (tid < 128) {
            int row = tid >> 2, qt = tid & 3;
            const _Float16* lp = lds + (size_t)row * LROW + qt * 24;
            float mx = 0.f;
#pragma unroll
            for (int j = 0; j < 24; ++j) mx = fmaxf(mx, fabsf((float)lp[j]));
            atomicMax(&rmaxb[row], __float_as_uint(mx));
        }
        __syncthreads();
        // quantize + store: 32 rows x 12 8B-chunks = 384 tasks
        for (int i = tid; i < 32 * 12; i += 192) {
            int row = i / 12, c = i - row * 12;
            int grow = n0b + row;
            if (grow >= n) continue;
            float rm = __uint_as_float(rmaxb[row]);
            float inv = (rm > 0.f) ? 127.0f / rm : 0.f;
            const _Float16* lp = lds + (size_t)row * LROW + c * 8;
            unsigned lo = 0, hi = 0;
#pragma unroll
            for (int j = 0; j < 4; ++j) {
                int qv = __float2int_rn((float)lp[j] * inv);
                qv = qv > 127 ? 127 : (qv < -127 ? -127 : qv);
                lo |= ((unsigned)qv & 255u) << (8 * j);
            }
#pragma unroll
            for (int j = 0; j < 4; ++j) {
                int qv = __float2int_rn((float)lp[4 + j] * inv);
                qv = qv > 127 ? 127 : (qv < -127 ? -127 : qv);
                hi |= ((unsigned)qv & 255u) << (8 * j);
            }
            *(uint2*)((unsigned char*)Yout + (size_t)grow * 96 + c * 8) =
                make_uint2(lo, hi);
            if (c == 0) sclo[grow] = rm * (1.0f / 127.0f);
        }
    } else {
        constexpr int CPR = FOUT / 8;
        for (int i = tid; i < 32 * CPR; i += 192) {
            int row = i / CPR, c = i - row * CPR;
            int grow = n0b + row;
            if (grow < n)
                *(uint4*)((_Float16*)Yout + (size_t)grow * FOUT + c * 8) =
                    *(const uint4*)(lds + (size_t)row * LROW + c * 8);
        }
    }
}

// ---------------- plain aggregation (layer 3: F=64 fp16 table, fp32 out) ------

__global__ __launch_bounds__(256) void k_aggr3(
    const _Float16* __restrict__ xw, const int* __restrict__ row_ptr,
    const unsigned* __restrict__ ep,
    const float* __restrict__ dis, const float* __restrict__ bias,
    float* __restrict__ out, int n) {
    constexpr int FQ = 8;
    int tg = blockIdx.x * 256 + threadIdx.x;
    int node = tg / FQ;
    int q = tg - node * FQ;
    if (node >= n) return;

    const uint4* __restrict__ base = (const uint4*)xw;
    float d = dis[node];
    float acc[8];
    {
        uint4 sv = base[(size_t)node * FQ + q];
        float t[8];
        cvt8(sv, t);
#pragma unroll
        for (int j = 0; j < 8; ++j) acc[j] = d * t[j];
    }
    gather_row<FQ>(base, ep, row_ptr[node], row_ptr[node + 1], q, acc);

    int fb = q * 8;
    const float4* bb = (const float4*)(bias + fb);
    float4 b0 = bb[0], b1 = bb[1];
    acc[0] = fmaf(acc[0], d, b0.x); acc[1] = fmaf(acc[1], d, b0.y);
    acc[2] = fmaf(acc[2], d, b0.z); acc[3] = fmaf(acc[3], d, b0.w);
    acc[4] = fmaf(acc[4], d, b1.x); acc[5] = fmaf(acc[5], d, b1.y);
    acc[6] = fmaf(acc[6], d, b1.z); acc[7] = fmaf(acc[7], d, b1.w);

    float* op = out + (size_t)node * 64 + fb;
    *(float4*)(op + 0) = make_float4(acc[0], acc[1], acc[2], acc[3]);
    *(float4*)(op + 4) = make_float4(acc[4], acc[5], acc[6], acc[7]);
}

// ---------------- launch ----------------

extern "C" void kernel_launch(void* const* d_in, const int* in_sizes, int n_in,
                              void* d_out, int out_size, void* d_ws, size_t ws_size,
                              hipStream_t stream) {
    constexpr int IN = 128, H = 96, OUT = 64;

    const float* x   = (const float*)d_in[0];
    const int*   ei  = (const int*)d_in[1];
    const float* ew  = (const float*)d_in[2];
    const float* W1  = (const float*)d_in[3];
    const float* b1  = (const float*)d_in[4];
    const float* W2  = (const float*)d_in[5];
    const float* b2  = (const float*)d_in[6];
    const float* W3  = (const float*)d_in[7];
    const float* b3  = (const float*)d_in[8];
    const float* g1  = (const float*)d_in[9];
    const float* be1 = (const float*)d_in[10];
    const float* m1  = (const float*)d_in[11];
    const float* v1  = (const float*)d_in[12];
    const float* g2  = (const float*)d_in[13];
    const float* be2 = (const float*)d_in[14];
    const float* m2  = (const float*)d_in[15];
    const float* v2  = (const float*)d_in[16];

    const int N = in_sizes[0] / IN;   // 50000
    const int E = in_sizes[2];        // 800000
    const int* row_idx = ei;
    const int* col_idx = ei + E;
    const int T1 = N / 3, T2 = 2 * (N / 3);

    char* ws = (char*)d_ws;
    size_t off = 0;
    auto alloc = [&](size_t bytes) -> void* {
        void* p = ws + off;
        off = (off + bytes + 255) & ~(size_t)255;
        return p;
    };
    unsigned long long* packed = (unsigned long long*)alloc((size_t)N * 8);
    float*     dis     = (float*)alloc((size_t)N * 4);
    int*       row_ptr = (int*)alloc((size_t)(N + 1) * 4);
    int*       bsum    = (int*)alloc(256 * 4);
    unsigned char* rank = (unsigned char*)alloc((size_t)E);
    unsigned*  ep      = (unsigned*)alloc((size_t)E * 4);
    _Float16*  w2h     = (_Float16*)alloc((size_t)H * H * 2);
    _Float16*  w3h     = (_Float16*)alloc((size_t)OUT * H * 2);
    unsigned char* t1q = (unsigned char*)alloc((size_t)N * 96);   // int8 XW1 rows
    float*     scl1    = (float*)alloc((size_t)N * 4);
    unsigned char* t2q = (unsigned char*)alloc((size_t)N * 96);   // int8 XW2 rows
    float*     scl2    = (float*)alloc((size_t)N * 4);
    _Float16*  buf64   = (_Float16*)alloc((size_t)N * OUT * 2);   // fp16 XW3 rows
    (void)ws_size; (void)n_in; (void)out_size;

    constexpr int W2N4 = H * H / 4, W3N4 = OUT * H / 4;   // 2304 + 1536 = 3840
    const int NB = (N + 255) / 256;          // 196 (<= 256 for scans)
    const int DEG1024 = (E + 1023) / 1024;   // 782
    const int GG = (N + 63) / 64;            // 782: 64 nodes/block
    const int PAIR = (DEG1024 > GG) ? DEG1024 : GG;   // 782
    const int CVT_B = (W2N4 + W3N4 + 255) / 256;      // 15

    hipMemsetAsync(packed, 0, (size_t)N * 8, stream);
    k_mega<<<2 * PAIR + CVT_B, 256, 0, stream>>>(
        row_idx, col_idx, ew, packed, rank, E, PAIR, T1, T2,
        x, W1, t1q, scl1, N, W2, W3, w2h, w3h, W2N4, W3N4);
    k_scan1<<<NB, 256, 0, stream>>>(packed, bsum, dis, N);
    k_scan23<<<NB, 256, 0, stream>>>(packed, bsum, row_ptr, N, E, NB);
    k_fill<<<(E + 255) / 256, 256, 0, stream>>>(row_idx, col_idx, ew, dis,
                                                row_ptr, rank, packed, ep, E, T1, T2);

    const int GF32 = (N + 31) / 32;                        // 1563 fused blocks
    const int GA64 = ((size_t)N * (OUT / 8) + 255) / 256;  // 1563

    // layer 1 int8-aggregation (16B reqs) + layer 2 transform -> int8 table 2
    k_aggr_mm<H, true><<<GF32, 192, 0, stream>>>(
        t1q, scl1, row_ptr, ep, dis, b1, g1, be1, m1, v1, w2h, t2q, scl2, N);

    // layer 2 int8-aggregation (16B reqs) + layer 3 transform -> fp16 XW3 rows
    k_aggr_mm<OUT, false><<<GF32, 192, 0, stream>>>(
        t2q, scl2, row_ptr, ep, dis, b2, g2, be2, m2, v2, w3h, buf64, nullptr, N);

    // layer 3 aggregation -> fp32 output
    k_aggr3<<<GA64, 256, 0, stream>>>(buf64, row_ptr, ep, dis, b3, (float*)d_out, N);
}

// Round 16
// 237.346 us; speedup vs baseline: 1.0405x; 1.0405x over previous
//
#include <hip/hip_runtime.h>
#include <hip/hip_fp16.h>

// GCN 3-layer: x -> GCNConv(W1)+BN+ReLU -> GCNConv(W2)+BN+ReLU -> GCNConv(W3)
// FINAL STRUCTURE (R23, measured 240.0us). Ledger:
// - k_mega: 800K memory-side RMW (op-rate-bound; width/scope/privatization
//   null R14/R18/R22) OVERLAPPED with LDS-staged gemm1 (R23: W1->LDS once per
//   block, -3.9us and decontended the atomic stream).
// - Gather (3 kernels, ~120us): line-service floor. Scheduling null (R13-16),
//   locality saturated (R17 -10us, R19 null), int8 rows -9.5us (R21),
//   request-width null (R24 +7, reverted).
// - Fusions: TLP-preserving aggr+MM (R20 -5us); R13's TLP-destroying variant
//   was -47us (reverted).
// CSR: u64 atomic/edge {wsum*2^17:24|c0:10|c1:10|c2:10} (source-third order),
// rank u8; fill is atomic-free. Tables: int8 row-quantized XW1/XW2 (2 lines/
// edge), fp16 XW3 (output precision).

constexpr float BN_EPS = 1e-5f;
constexpr float DEG_SCALE = 131072.0f;            // 2^17 (weighted degree, 24-bit field)
constexpr float INV_DEG_SCALE = 1.0f / 131072.0f;
constexpr float NORM_SCALE = 32768.0f;            // 2^15 (edge norm quant)
constexpr float INV_NORM_SCALE = 1.0f / 32768.0f;

typedef _Float16 f16x8 __attribute__((ext_vector_type(8)));
typedef float f32x4 __attribute__((ext_vector_type(4)));

// ---------------- gemm1 (k_mega role): [64x128]@W1^T -> int8 rows + scale ----
// lds: union buffer, 96*136 = 13056 halves (26112B).
//   phase 1: W1 staged fp16 at [96][136] (row stride 272B, 16B-aligned)
//   phase 2 (after barrier): acc epilogue rows [64][104]

__device__ __forceinline__ void gemm1_q(const float* __restrict__ x,
                                        const float* __restrict__ W1,
                                        unsigned char* __restrict__ t1q,
                                        float* __restrict__ scl1,
                                        int n0b, int tid, int n,
                                        _Float16* lds, unsigned* rmaxb) {
    constexpr int LROW = 104;
    constexpr int WROW = 136;
    if (tid < 64) rmaxb[tid] = 0u;
    // ---- stage W1 -> LDS fp16 (coalesced, once per block) ----
    for (int i = tid; i < 96 * 128; i += 256) {
        int row = i >> 7, col = i & 127;
        lds[row * WROW + col] = (_Float16)W1[i];
    }
    __syncthreads();

    int wave = tid >> 6, lane = tid & 63, quad = lane >> 4, r = lane & 15;
    int n0 = n0b + wave * 16;
    bool active = (n0 < n);             // N%16==0: active waves fully in-bounds
    f32x4 acc[6];
    if (active) {
        f16x8 a[4];
        const float* xr = x + (size_t)(n0 + r) * 128 + quad * 8;
#pragma unroll
        for (int kt = 0; kt < 4; ++kt) {
            float4 v0 = *(const float4*)(xr + kt * 32);
            float4 v1 = *(const float4*)(xr + kt * 32 + 4);
            f16x8 t = {(_Float16)v0.x, (_Float16)v0.y, (_Float16)v0.z, (_Float16)v0.w,
                       (_Float16)v1.x, (_Float16)v1.y, (_Float16)v1.z, (_Float16)v1.w};
            a[kt] = t;
        }
#pragma unroll
        for (int ft = 0; ft < 6; ++ft) acc[ft] = (f32x4){0.f, 0.f, 0.f, 0.f};
#pragma unroll
        for (int kt = 0; kt < 4; ++kt) {
#pragma unroll
            for (int ft = 0; ft < 6; ++ft) {
                f16x8 b = *(const f16x8*)(lds + (size_t)(ft * 16 + r) * WROW + kt * 32 + quad * 8);
                acc[ft] = __builtin_amdgcn_mfma_f32_16x16x32_f16(a[kt], b, acc[ft], 0, 0, 0);
            }
        }
    }
    __syncthreads();                    // all B-reads done before buffer reuse
    if (active) {
#pragma unroll
        for (int ft = 0; ft < 6; ++ft)
#pragma unroll
            for (int reg = 0; reg < 4; ++reg)
                lds[(size_t)(wave * 16 + quad * 4 + reg) * LROW + ft * 16 + r] =
                    (_Float16)acc[ft][reg];
    }
    __syncthreads();
    {   // row absmax: 64 rows x 4 quarters (24 vals)
        int row = tid >> 2, qt = tid & 3;
        const _Float16* lp = lds + (size_t)row * LROW + qt * 24;
        float mx = 0.f;
#pragma unroll
        for (int j = 0; j < 24; ++j) mx = fmaxf(mx, fabsf((float)lp[j]));
        atomicMax(&rmaxb[row], __float_as_uint(mx));
    }
    __syncthreads();
    for (int i = tid; i < 64 * 12; i += 256) {   // quantize + store
        int row = i / 12, c = i - row * 12;
        int grow = n0b + row;
        if (grow >= n) continue;
        float rm = __uint_as_float(rmaxb[row]);
        float inv = (rm > 0.f) ? 127.0f / rm : 0.f;
        const _Float16* lp = lds + (size_t)row * LROW + c * 8;
        unsigned lo = 0, hi = 0;
#pragma unroll
        for (int j = 0; j < 4; ++j) {
            int qv = __float2int_rn((float)lp[j] * inv);
            qv = qv > 127 ? 127 : (qv < -127 ? -127 : qv);
            lo |= ((unsigned)qv & 255u) << (8 * j);
        }
#pragma unroll
        for (int j = 0; j < 4; ++j) {
            int qv = __float2int_rn((float)lp[4 + j] * inv);
            qv = qv > 127 ? 127 : (qv < -127 ? -127 : qv);
            hi |= ((unsigned)qv & 255u) << (8 * j);
        }
        *(uint2*)(t1q + (size_t)grow * 96 + c * 8) = make_uint2(lo, hi);
        if (c == 0) scl1[grow] = rm * (1.0f / 127.0f);
    }
}

// ---------------- mega: interleaved deg atomics | GEMM1(int8) | W convert -----

__global__ __launch_bounds__(256) void k_mega(
    const int* __restrict__ row_idx, const int* __restrict__ col_idx,
    const float* __restrict__ ew,
    unsigned long long* packed, unsigned char* rank, int e_cnt, int pair_b,
    int t1, int t2,
    const float* __restrict__ x, const float* __restrict__ W1,
    unsigned char* __restrict__ t1q, float* __restrict__ scl1, int n,
    const float* __restrict__ W2, const float* __restrict__ W3,
    _Float16* __restrict__ w2h, _Float16* __restrict__ w3h,
    int w2n4, int w3n4) {
    __shared__ _Float16 lds[96 * 136];     // union: W1 stage / epilogue rows
    __shared__ unsigned rmaxb[64];
    int b = blockIdx.x;
    if (b < 2 * pair_b) {
        int q = b >> 1;
        if ((b & 1) == 0) {
            // deg role: 1024 edges per block (4 independent atomics/thread)
#pragma unroll
            for (int j = 0; j < 4; ++j) {
                int e = q * 1024 + j * 256 + (int)threadIdx.x;
                if (e < e_cnt) {
                    int c = col_idx[e];
                    int r = row_idx[e];
                    int t = (r >= t2) ? 2 : ((r >= t1) ? 1 : 0);
                    int sh = 24 + 10 * t;
                    unsigned wfix = (unsigned)(ew[e] * DEG_SCALE + 0.5f);
                    unsigned long long inc = (1ull << sh) | (unsigned long long)wfix;
                    unsigned long long old = atomicAdd(&packed[c], inc);
                    rank[e] = (unsigned char)((old >> sh) & 0x3FFull);
                }
            }
        } else {
            gemm1_q(x, W1, t1q, scl1, q * 64, (int)threadIdx.x, n, lds, rmaxb);
        }
    } else {
        // convert role: W2|W3 fp32->fp16
        int i = (b - 2 * pair_b) * 256 + (int)threadIdx.x;
        const float* src; _Float16* dst; int o;
        if (i < w2n4) { src = W2; dst = w2h; o = i; }
        else if (i < w2n4 + w3n4) { src = W3; dst = w3h; o = i - w2n4; }
        else return;
        float4 v = ((const float4*)src)[o];
        __half2 h0 = __floats2half2_rn(v.x, v.y);
        __half2 h1 = __floats2half2_rn(v.z, v.w);
        *(uint2*)(dst + (size_t)o * 4) = make_uint2(*(unsigned*)&h0, *(unsigned*)&h1);
    }
}

// ---------------- scans ----------------

__device__ __forceinline__ int pk_cnt(unsigned long long p) {
    return (int)((p >> 24) & 0x3FF) + (int)((p >> 34) & 0x3FF) + (int)((p >> 44) & 0x3FF);
}

__global__ void k_scan1(const unsigned long long* __restrict__ packed,
                        int* bsum, float* dis, int n) {
    __shared__ int s[256];
    int i = blockIdx.x * 256 + threadIdx.x;
    int cnt = 0;
    if (i < n) {
        unsigned long long p = packed[i];
        cnt = pk_cnt(p);
        float wsum = (float)(unsigned)(p & 0xFFFFFFull) * INV_DEG_SCALE;
        dis[i] = rsqrtf(1.0f + wsum);   // self-loop weight 1 included
    }
    s[threadIdx.x] = cnt;
    __syncthreads();
    for (int off = 128; off > 0; off >>= 1) {
        if ((int)threadIdx.x < off) s[threadIdx.x] += s[threadIdx.x + off];
        __syncthreads();
    }
    if (threadIdx.x == 0) bsum[blockIdx.x] = s[0];
}

__global__ void k_scan23(const unsigned long long* __restrict__ packed,
                         const int* __restrict__ bsum,
                         int* row_ptr, int n, int e_total, int nb) {
    __shared__ int sb[256];
    __shared__ int s[256];
    int t = threadIdx.x;
    int bv = (t < nb) ? bsum[t] : 0;
    sb[t] = bv;
    __syncthreads();
    for (int off = 1; off < 256; off <<= 1) {
        int x = (t >= off) ? sb[t - off] : 0;
        __syncthreads();
        sb[t] += x;
        __syncthreads();
    }
    int boff = (blockIdx.x == 0) ? 0 : sb[blockIdx.x - 1];

    int i = blockIdx.x * 256 + t;
    int v = (i < n) ? pk_cnt(packed[i]) : 0;
    s[t] = v;
    __syncthreads();
    for (int off = 1; off < 256; off <<= 1) {
        int x = (t >= off) ? s[t - off] : 0;
        __syncthreads();
        s[t] += x;
        __syncthreads();
    }
    int ex = s[t] - v + boff;
    if (i < n) row_ptr[i] = ex;
    if (i == 0) row_ptr[n] = e_total;
}

__global__ void k_fill(const int* __restrict__ row_idx, const int* __restrict__ col_idx,
                       const float* __restrict__ ew, const float* __restrict__ dis,
                       const int* __restrict__ row_ptr, const unsigned char* __restrict__ rank,
                       const unsigned long long* __restrict__ packed,
                       unsigned* ep, int e_cnt, int t1, int t2) {
    int e = blockIdx.x * 256 + threadIdx.x;
    if (e < e_cnt) {
        int r = row_idx[e];
        int c = col_idx[e];
        unsigned long long p = packed[c];          // 400KB table: L2-resident
        int c0 = (int)((p >> 24) & 0x3FF);
        int c1 = (int)((p >> 34) & 0x3FF);
        int t = (r >= t2) ? 2 : ((r >= t1) ? 1 : 0);
        int off = (t > 0 ? c0 : 0) + (t > 1 ? c1 : 0);
        float nm = dis[r] * ew[e];                 // dis[c] factored into aggr
        unsigned q = (unsigned)(nm * NORM_SCALE + 0.5f);
        if (q > 65535u) q = 65535u;
        ep[row_ptr[c] + off + (int)rank[e]] = ((unsigned)r << 16) | q;
    }
}

// ---------------- aggregation helpers (R21) ----------------

__device__ inline void cvt8(uint4 u, float* f) {
    float2 t;
    t = __half22float2(*(const __half2*)&u.x); f[0] = t.x; f[1] = t.y;
    t = __half22float2(*(const __half2*)&u.y); f[2] = t.x; f[3] = t.y;
    t = __half22float2(*(const __half2*)&u.z); f[4] = t.x; f[5] = t.y;
    t = __half22float2(*(const __half2*)&u.w); f[6] = t.x; f[7] = t.y;
}

__device__ inline void h8_acc(uint4 u, float w, float acc[8]) {
    float2 a = __half22float2(*(const __half2*)&u.x);
    float2 b = __half22float2(*(const __half2*)&u.y);
    float2 c = __half22float2(*(const __half2*)&u.z);
    float2 d = __half22float2(*(const __half2*)&u.w);
    acc[0] = fmaf(w, a.x, acc[0]); acc[1] = fmaf(w, a.y, acc[1]);
    acc[2] = fmaf(w, b.x, acc[2]); acc[3] = fmaf(w, b.y, acc[3]);
    acc[4] = fmaf(w, c.x, acc[4]); acc[5] = fmaf(w, c.y, acc[5]);
    acc[6] = fmaf(w, d.x, acc[6]); acc[7] = fmaf(w, d.y, acc[7]);
}

__device__ inline void q8_acc(uint2 v, float ws, float acc[8]) {
    int a = (int)v.x, b = (int)v.y;
    acc[0] = fmaf(ws, (float)(int)(char)(a      ), acc[0]);
    acc[1] = fmaf(ws, (float)(int)(char)(a >>  8), acc[1]);
    acc[2] = fmaf(ws, (float)(int)(char)(a >> 16), acc[2]);
    acc[3] = fmaf(ws, (float)(a >> 24),            acc[3]);
    acc[4] = fmaf(ws, (float)(int)(char)(b      ), acc[4]);
    acc[5] = fmaf(ws, (float)(int)(char)(b >>  8), acc[5]);
    acc[6] = fmaf(ws, (float)(int)(char)(b >> 16), acc[6]);
    acc[7] = fmaf(ws, (float)(b >> 24),            acc[7]);
}

__device__ __forceinline__ void gather_row_q(const unsigned char* __restrict__ tq,
                                             const float* __restrict__ scl,
                                             const unsigned* __restrict__ ep,
                                             int e0, int e1, int q, float acc[8]) {
    int e = e0;
    for (; e + 4 <= e1; e += 4) {
        unsigned p0 = ep[e + 0], p1 = ep[e + 1], p2 = ep[e + 2], p3 = ep[e + 3];
        uint2 v0 = *(const uint2*)(tq + (size_t)(p0 >> 16) * 96 + q * 8);
        uint2 v1 = *(const uint2*)(tq + (size_t)(p1 >> 16) * 96 + q * 8);
        uint2 v2 = *(const uint2*)(tq + (size_t)(p2 >> 16) * 96 + q * 8);
        uint2 v3 = *(const uint2*)(tq + (size_t)(p3 >> 16) * 96 + q * 8);
        float s0 = scl[p0 >> 16], s1 = scl[p1 >> 16];
        float s2 = scl[p2 >> 16], s3 = scl[p3 >> 16];
        q8_acc(v0, (float)(p0 & 0xffffu) * INV_NORM_SCALE * s0, acc);
        q8_acc(v1, (float)(p1 & 0xffffu) * INV_NORM_SCALE * s1, acc);
        q8_acc(v2, (float)(p2 & 0xffffu) * INV_NORM_SCALE * s2, acc);
        q8_acc(v3, (float)(p3 & 0xffffu) * INV_NORM_SCALE * s3, acc);
    }
    for (; e < e1; ++e) {
        unsigned p = ep[e];
        uint2 v = *(const uint2*)(tq + (size_t)(p >> 16) * 96 + q * 8);
        q8_acc(v, (float)(p & 0xffffu) * INV_NORM_SCALE * scl[p >> 16], acc);
    }
}

template <int FQ>
__device__ __forceinline__ void gather_row(const uint4* __restrict__ base,
                                           const unsigned* __restrict__ ep,
                                           int e0, int e1, int q, float acc[8]) {
    int e = e0;
    for (; e + 8 <= e1; e += 8) {
        unsigned p0 = ep[e + 0], p1 = ep[e + 1], p2 = ep[e + 2], p3 = ep[e + 3];
        unsigned p4 = ep[e + 4], p5 = ep[e + 5], p6 = ep[e + 6], p7 = ep[e + 7];
        uint4 x0 = base[(size_t)(p0 >> 16) * FQ + q];
        uint4 x1 = base[(size_t)(p1 >> 16) * FQ + q];
        uint4 x2 = base[(size_t)(p2 >> 16) * FQ + q];
        uint4 x3 = base[(size_t)(p3 >> 16) * FQ + q];
        uint4 x4 = base[(size_t)(p4 >> 16) * FQ + q];
        uint4 x5 = base[(size_t)(p5 >> 16) * FQ + q];
        uint4 x6 = base[(size_t)(p6 >> 16) * FQ + q];
        uint4 x7 = base[(size_t)(p7 >> 16) * FQ + q];
        h8_acc(x0, (float)(p0 & 0xffffu) * INV_NORM_SCALE, acc);
        h8_acc(x1, (float)(p1 & 0xffffu) * INV_NORM_SCALE, acc);
        h8_acc(x2, (float)(p2 & 0xffffu) * INV_NORM_SCALE, acc);
        h8_acc(x3, (float)(p3 & 0xffffu) * INV_NORM_SCALE, acc);
        h8_acc(x4, (float)(p4 & 0xffffu) * INV_NORM_SCALE, acc);
        h8_acc(x5, (float)(p5 & 0xffffu) * INV_NORM_SCALE, acc);
        h8_acc(x6, (float)(p6 & 0xffffu) * INV_NORM_SCALE, acc);
        h8_acc(x7, (float)(p7 & 0xffffu) * INV_NORM_SCALE, acc);
    }
    for (; e + 4 <= e1; e += 4) {
        unsigned p0 = ep[e + 0], p1 = ep[e + 1], p2 = ep[e + 2], p3 = ep[e + 3];
        uint4 x0 = base[(size_t)(p0 >> 16) * FQ + q];
        uint4 x1 = base[(size_t)(p1 >> 16) * FQ + q];
        uint4 x2 = base[(size_t)(p2 >> 16) * FQ + q];
        uint4 x3 = base[(size_t)(p3 >> 16) * FQ + q];
        h8_acc(x0, (float)(p0 & 0xffffu) * INV_NORM_SCALE, acc);
        h8_acc(x1, (float)(p1 & 0xffffu) * INV_NORM_SCALE, acc);
        h8_acc(x2, (float)(p2 & 0xffffu) * INV_NORM_SCALE, acc);
        h8_acc(x3, (float)(p3 & 0xffffu) * INV_NORM_SCALE, acc);
    }
    for (; e < e1; ++e) {
        unsigned p = ep[e];
        uint4 xv = base[(size_t)(p >> 16) * FQ + q];
        h8_acc(xv, (float)(p & 0xffffu) * INV_NORM_SCALE, acc);
    }
}

// ---------------- fused: int8-aggregate(96) + BN + ReLU + [16x96]@W^T ----------

template <int FOUT, bool QOUT>
__global__ __launch_bounds__(192) void k_aggr_mm(
    const unsigned char* __restrict__ tq, const float* __restrict__ scl,
    const int* __restrict__ row_ptr, const unsigned* __restrict__ ep,
    const float* __restrict__ dis, const float* __restrict__ bias,
    const float* __restrict__ g, const float* __restrict__ beta,
    const float* __restrict__ m, const float* __restrict__ v,
    const _Float16* __restrict__ Wh,       // [FOUT][96] fp16
    void* __restrict__ Yout, float* __restrict__ sclo, int n) {
    constexpr int LROW = 104;
    __shared__ _Float16 lds[16 * LROW];
    __shared__ unsigned rmaxb[16];
    int tid = (int)threadIdx.x;
    int n0b = blockIdx.x * 16;
    int nl = tid / 12;                     // 0..15
    int q = tid - nl * 12;                 // 0..11
    int node = n0b + nl;
    if (QOUT && tid < 16) rmaxb[tid] = 0u;

    if (node < n) {
        float d = dis[node];
        float acc[8];
#pragma unroll
        for (int j = 0; j < 8; ++j) acc[j] = 0.f;
        {
            uint2 sv = *(const uint2*)(tq + (size_t)node * 96 + q * 8);
            q8_acc(sv, d * scl[node], acc);
        }
        gather_row_q(tq, scl, ep, row_ptr[node], row_ptr[node + 1], q, acc);

        int fb = q * 8;
        const float4* bb = (const float4*)(bias + fb);
        float4 b0 = bb[0], b1 = bb[1];
        acc[0] = fmaf(acc[0], d, b0.x); acc[1] = fmaf(acc[1], d, b0.y);
        acc[2] = fmaf(acc[2], d, b0.z); acc[3] = fmaf(acc[3], d, b0.w);
        acc[4] = fmaf(acc[4], d, b1.x); acc[5] = fmaf(acc[5], d, b1.y);
        acc[6] = fmaf(acc[6], d, b1.z); acc[7] = fmaf(acc[7], d, b1.w);
#pragma unroll
        for (int j = 0; j < 8; ++j) {
            acc[j] = fmaxf((acc[j] - m[fb + j]) * rsqrtf(v[fb + j] + BN_EPS) * g[fb + j]
                           + beta[fb + j], 0.f);
        }
        __half2 h0 = __floats2half2_rn(acc[0], acc[1]);
        __half2 h1 = __floats2half2_rn(acc[2], acc[3]);
        __half2 h2 = __floats2half2_rn(acc[4], acc[5]);
        __half2 h3 = __floats2half2_rn(acc[6], acc[7]);
        *(uint4*)(lds + (size_t)nl * LROW + fb) =
            make_uint4(*(unsigned*)&h0, *(unsigned*)&h1, *(unsigned*)&h2, *(unsigned*)&h3);
    }
    __syncthreads();

    constexpr int FT = FOUT / 16;
    f32x4 cacc[FT];
    int quad = tid >> 4, r = tid & 15;
    if (tid < 64) {
        f16x8 a[3];
#pragma unroll
        for (int kt = 0; kt < 3; ++kt)
            a[kt] = *(const f16x8*)(lds + (size_t)r * LROW + kt * 32 + quad * 8);
#pragma unroll
        for (int ft = 0; ft < FT; ++ft) cacc[ft] = (f32x4){0.f, 0.f, 0.f, 0.f};
#pragma unroll
        for (int kt = 0; kt < 3; ++kt) {
#pragma unroll
            for (int ft = 0; ft < FT; ++ft) {
                f16x8 b = *(const f16x8*)(Wh + (size_t)(ft * 16 + r) * 96 + kt * 32 + quad * 8);
                cacc[ft] = __builtin_amdgcn_mfma_f32_16x16x32_f16(a[kt], b, cacc[ft], 0, 0, 0);
            }
        }
    }
    __syncthreads();
    if (tid < 64) {
#pragma unroll
        for (int ft = 0; ft < FT; ++ft)
#pragma unroll
            for (int reg = 0; reg < 4; ++reg)
                lds[(size_t)(quad * 4 + reg) * LROW + ft * 16 + r] = (_Float16)cacc[ft][reg];
    }
    __syncthreads();

    if (QOUT) {
        if (tid < 64) {
            int row = tid >> 2, qt = tid & 3;
            const _Float16* lp = lds + (size_t)row * LROW + qt * 24;
            float mx = 0.f;
#pragma unroll
            for (int j = 0; j < 24; ++j) mx = fmaxf(mx, fabsf((float)lp[j]));
            atomicMax(&rmaxb[row], __float_as_uint(mx));
        }
        __syncthreads();
        {
            int row = nl, c = q;
            int grow = n0b + row;
            if (grow < n) {
                float rm = __uint_as_float(rmaxb[row]);
                float inv = (rm > 0.f) ? 127.0f / rm : 0.f;
                const _Float16* lp = lds + (size_t)row * LROW + c * 8;
                unsigned lo = 0, hi = 0;
#pragma unroll
                for (int j = 0; j < 4; ++j) {
                    int qv = __float2int_rn((float)lp[j] * inv);
                    qv = qv > 127 ? 127 : (qv < -127 ? -127 : qv);
                    lo |= ((unsigned)qv & 255u) << (8 * j);
                }
#pragma unroll
                for (int j = 0; j < 4; ++j) {
                    int qv = __float2int_rn((float)lp[4 + j] * inv);
                    qv = qv > 127 ? 127 : (qv < -127 ? -127 : qv);
                    hi |= ((unsigned)qv & 255u) << (8 * j);
                }
                *(uint2*)((unsigned char*)Yout + (size_t)grow * 96 + c * 8) =
                    make_uint2(lo, hi);
                if (c == 0) sclo[grow] = rm * (1.0f / 127.0f);
            }
        }
    } else {
        constexpr int CPR = FOUT / 8;
        for (int i = tid; i < 16 * CPR; i += 192) {
            int row = i / CPR, c = i - row * CPR;
            int grow = n0b + row;
            if (grow < n)
                *(uint4*)((_Float16*)Yout + (size_t)grow * FOUT + c * 8) =
                    *(const uint4*)(lds + (size_t)row * LROW + c * 8);
        }
    }
}

// ---------------- plain aggregation (layer 3: F=64 fp16 table, fp32 out) ------

__global__ __launch_bounds__(256) void k_aggr3(
    const _Float16* __restrict__ xw, const int* __restrict__ row_ptr,
    const unsigned* __restrict__ ep,
    const float* __restrict__ dis, const float* __restrict__ bias,
    float* __restrict__ out, int n) {
    constexpr int FQ = 8;
    int tg = blockIdx.x * 256 + threadIdx.x;
    int node = tg / FQ;
    int q = tg - node * FQ;
    if (node >= n) return;

    const uint4* __restrict__ base = (const uint4*)xw;
    float d = dis[node];
    float acc[8];
    {
        uint4 sv = base[(size_t)node * FQ + q];
        float t[8];
        cvt8(sv, t);
#pragma unroll
        for (int j = 0; j < 8; ++j) acc[j] = d * t[j];
    }
    gather_row<FQ>(base, ep, row_ptr[node], row_ptr[node + 1], q, acc);

    int fb = q * 8;
    const float4* bb = (const float4*)(bias + fb);
    float4 b0 = bb[0], b1 = bb[1];
    acc[0] = fmaf(acc[0], d, b0.x); acc[1] = fmaf(acc[1], d, b0.y);
    acc[2] = fmaf(acc[2], d, b0.z); acc[3] = fmaf(acc[3], d, b0.w);
    acc[4] = fmaf(acc[4], d, b1.x); acc[5] = fmaf(acc[5], d, b1.y);
    acc[6] = fmaf(acc[6], d, b1.z); acc[7] = fmaf(acc[7], d, b1.w);

    float* op = out + (size_t)node * 64 + fb;
    *(float4*)(op + 0) = make_float4(acc[0], acc[1], acc[2], acc[3]);
    *(float4*)(op + 4) = make_float4(acc[4], acc[5], acc[6], acc[7]);
}

// ---------------- launch ----------------

extern "C" void kernel_launch(void* const* d_in, const int* in_sizes, int n_in,
                              void* d_out, int out_size, void* d_ws, size_t ws_size,
                              hipStream_t stream) {
    constexpr int IN = 128, H = 96, OUT = 64;

    const float* x   = (const float*)d_in[0];
    const int*   ei  = (const int*)d_in[1];
    const float* ew  = (const float*)d_in[2];
    const float* W1  = (const float*)d_in[3];
    const float* b1  = (const float*)d_in[4];
    const float* W2  = (const float*)d_in[5];
    const float* b2  = (const float*)d_in[6];
    const float* W3  = (const float*)d_in[7];
    const float* b3  = (const float*)d_in[8];
    const float* g1  = (const float*)d_in[9];
    const float* be1 = (const float*)d_in[10];
    const float* m1  = (const float*)d_in[11];
    const float* v1  = (const float*)d_in[12];
    const float* g2  = (const float*)d_in[13];
    const float* be2 = (const float*)d_in[14];
    const float* m2  = (const float*)d_in[15];
    const float* v2  = (const float*)d_in[16];

    const int N = in_sizes[0] / IN;   // 50000
    const int E = in_sizes[2];        // 800000
    const int* row_idx = ei;
    const int* col_idx = ei + E;
    const int T1 = N / 3, T2 = 2 * (N / 3);

    char* ws = (char*)d_ws;
    size_t off = 0;
    auto alloc = [&](size_t bytes) -> void* {
        void* p = ws + off;
        off = (off + bytes + 255) & ~(size_t)255;
        return p;
    };
    unsigned long long* packed = (unsigned long long*)alloc((size_t)N * 8);
    float*     dis     = (float*)alloc((size_t)N * 4);
    int*       row_ptr = (int*)alloc((size_t)(N + 1) * 4);
    int*       bsum    = (int*)alloc(256 * 4);
    unsigned char* rank = (unsigned char*)alloc((size_t)E);
    unsigned*  ep      = (unsigned*)alloc((size_t)E * 4);
    _Float16*  w2h     = (_Float16*)alloc((size_t)H * H * 2);
    _Float16*  w3h     = (_Float16*)alloc((size_t)OUT * H * 2);
    unsigned char* t1q = (unsigned char*)alloc((size_t)N * 96);   // int8 XW1 rows
    float*     scl1    = (float*)alloc((size_t)N * 4);
    unsigned char* t2q = (unsigned char*)alloc((size_t)N * 96);   // int8 XW2 rows
    float*     scl2    = (float*)alloc((size_t)N * 4);
    _Float16*  buf64   = (_Float16*)alloc((size_t)N * OUT * 2);   // fp16 XW3 rows
    (void)ws_size; (void)n_in; (void)out_size;

    constexpr int W2N4 = H * H / 4, W3N4 = OUT * H / 4;   // 2304 + 1536 = 3840
    const int NB = (N + 255) / 256;          // 196 (<= 256 for scans)
    const int DEG1024 = (E + 1023) / 1024;   // 782
    const int GG = (N + 63) / 64;            // 782: 64 nodes/block
    const int PAIR = (DEG1024 > GG) ? DEG1024 : GG;   // 782
    const int CVT_B = (W2N4 + W3N4 + 255) / 256;      // 15

    hipMemsetAsync(packed, 0, (size_t)N * 8, stream);
    k_mega<<<2 * PAIR + CVT_B, 256, 0, stream>>>(
        row_idx, col_idx, ew, packed, rank, E, PAIR, T1, T2,
        x, W1, t1q, scl1, N, W2, W3, w2h, w3h, W2N4, W3N4);
    k_scan1<<<NB, 256, 0, stream>>>(packed, bsum, dis, N);
    k_scan23<<<NB, 256, 0, stream>>>(packed, bsum, row_ptr, N, E, NB);
    k_fill<<<(E + 255) / 256, 256, 0, stream>>>(row_idx, col_idx, ew, dis,
                                                row_ptr, rank, packed, ep, E, T1, T2);

    const int GF = (N + 15) / 16;                          // 3125 fused blocks
    const int GA64 = ((size_t)N * (OUT / 8) + 255) / 256;  // 1563

    // layer 1 int8-aggregation + layer 2 transform -> int8 table 2
    k_aggr_mm<H, true><<<GF, 192, 0, stream>>>(
        t1q, scl1, row_ptr, ep, dis, b1, g1, be1, m1, v1, w2h, t2q, scl2, N);

    // layer 2 int8-aggregation + layer 3 transform -> fp16 XW3 rows
    k_aggr_mm<OUT, false><<<GF, 192, 0, stream>>>(
        t2q, scl2, row_ptr, ep, dis, b2, g2, be2, m2, v2, w3h, buf64, nullptr, N);

    // layer 3 aggregation -> fp32 output
    k_aggr3<<<GA64, 256, 0, stream>>>(buf64, row_ptr, ep, dis, b3, (float*)d_out, N);
}